// Round 1
// baseline (284.783 us; speedup 1.0000x reference)
//
#include <hip/hip_runtime.h>
#include <hip/hip_bf16.h>

// MoE combiner: out[i,:] = sum_e gates[i,e] * expert_outputs[e,:]
// expert_outputs: [64, 4096] f32   (d_in[0])
// gates:          [16384, 64] f32  (d_in[1], top-2 sparse per row)
// out:            [16384, 4096] f32
//
// Memory-bound: 256 MB output writes dominate. Expert table (1 MB) lives in L2.

#define NUM_EXPERTS 64
#define D_MODEL 4096
#define NUM_IMAGES 16384
#define D4 (D_MODEL / 4)   // 1024 float4 per row

__global__ __launch_bounds__(256) void moe_combine_kernel(
    const float* __restrict__ expert,   // [64, 4096]
    const float* __restrict__ gates,    // [16384, 64]
    float* __restrict__ out)            // [16384, 4096]
{
    const int row = blockIdx.x;
    const int t   = threadIdx.x;

    __shared__ float sg[NUM_EXPERTS];
    __shared__ int   se[NUM_EXPERTS];
    __shared__ int   scount;

    if (t == 0) scount = 0;
    __syncthreads();

    // Threads 0..63 (first wave) compact nonzero gates for this row.
    if (t < NUM_EXPERTS) {
        float g = gates[(size_t)row * NUM_EXPERTS + t];
        if (g != 0.0f) {
            int k = atomicAdd(&scount, 1);
            sg[k] = g;
            se[k] = t;
        }
    }
    __syncthreads();

    const int cnt = scount;   // typically 2

    const float4* __restrict__ E = (const float4*)expert;
    float4* __restrict__ O = (float4*)out;

    // 1024 float4 chunks per row, 256 threads -> 4 chunks/thread, coalesced.
    #pragma unroll
    for (int c = t; c < D4; c += 256) {
        float4 acc = make_float4(0.f, 0.f, 0.f, 0.f);
        for (int j = 0; j < cnt; ++j) {
            const float g = sg[j];
            const float4 v = E[(size_t)se[j] * D4 + c];
            acc.x += g * v.x;
            acc.y += g * v.y;
            acc.z += g * v.z;
            acc.w += g * v.w;
        }
        O[(size_t)row * D4 + c] = acc;
    }
}

extern "C" void kernel_launch(void* const* d_in, const int* in_sizes, int n_in,
                              void* d_out, int out_size, void* d_ws, size_t ws_size,
                              hipStream_t stream) {
    const float* expert = (const float*)d_in[0];  // [64, 4096]
    const float* gates  = (const float*)d_in[1];  // [16384, 64]
    float* out = (float*)d_out;                   // [16384, 4096]

    dim3 grid(NUM_IMAGES);
    dim3 block(256);
    moe_combine_kernel<<<grid, block, 0, stream>>>(expert, gates, out);
}

// Round 3
// 275.505 us; speedup vs baseline: 1.0337x; 1.0337x over previous
//
#include <hip/hip_runtime.h>
#include <hip/hip_bf16.h>

// MoE combiner: out[i,:] = sum_e gates[i,e] * expert_outputs[e,:]
// expert_outputs: [64, 4096] f32   (d_in[0])
// gates:          [16384, 64] f32  (d_in[1], exactly top-2 nonzero per row)
// out:            [16384, 4096] f32
//
// Write-roofline bound (~256 MB out). Key: NON-TEMPORAL output stores so the
// streaming writes don't thrash per-XCD L2 (4 MB) — keeps the 1 MB expert
// table L2-resident for the ~512 MB of logical expert-row re-reads.
//
// NOTE: __builtin_nontemporal_store needs a clang ext_vector_type, not HIP's
// struct float4 — hence v4f below.

#define NUM_EXPERTS 64
#define D_MODEL 4096
#define NUM_IMAGES 16384
#define D4 (D_MODEL / 4)          // 1024 float4 per row
#define ROWS_PER_BLOCK 4

typedef float v4f __attribute__((ext_vector_type(4)));

__global__ __launch_bounds__(256) void moe_combine_kernel(
    const float* __restrict__ expert,   // [64, 4096]
    const float* __restrict__ gates,    // [16384, 64]
    float* __restrict__ out)            // [16384, 4096]
{
    const int row0 = blockIdx.x * ROWS_PER_BLOCK;
    const int tid  = threadIdx.x;
    const int wave = tid >> 6;          // 0..3 — wave w compacts row row0+w
    const int lane = tid & 63;

    __shared__ float sg[ROWS_PER_BLOCK][NUM_EXPERTS];
    __shared__ int   se[ROWS_PER_BLOCK][NUM_EXPERTS];
    __shared__ int   scnt[ROWS_PER_BLOCK];

    // Ballot-based compaction: no atomics, one barrier for 4 rows.
    {
        const int r = row0 + wave;
        const float g = gates[(size_t)r * NUM_EXPERTS + lane];
        const unsigned long long m = __ballot(g != 0.0f);
        if (g != 0.0f) {
            const int pos = __popcll(m & ((1ull << lane) - 1ull));
            sg[wave][pos] = g;
            se[wave][pos] = lane;
        }
        if (lane == 0) scnt[wave] = (int)__popcll(m);
    }
    __syncthreads();

    const v4f* __restrict__ E = (const v4f*)expert;

    for (int r = 0; r < ROWS_PER_BLOCK; ++r) {
        const int row = row0 + r;
        const int cnt = scnt[r];
        v4f* __restrict__ Orow = (v4f*)out + (size_t)row * D4;

        if (cnt == 2) {
            // Fast path: exactly top-2 (always, for this routing).
            const float g0 = sg[r][0], g1 = sg[r][1];
            const v4f* __restrict__ E0 = E + (size_t)se[r][0] * D4;
            const v4f* __restrict__ E1 = E + (size_t)se[r][1] * D4;
            #pragma unroll
            for (int c = tid; c < D4; c += 256) {
                const v4f v0 = E0[c];
                const v4f v1 = E1[c];
                const v4f acc = g0 * v0 + g1 * v1;
                __builtin_nontemporal_store(acc, &Orow[c]);
            }
        } else {
            // Generic fallback (cnt != 2), still correct.
            for (int c = tid; c < D4; c += 256) {
                v4f acc = (v4f)(0.0f);
                for (int j = 0; j < cnt; ++j) {
                    acc += sg[r][j] * E[(size_t)se[r][j] * D4 + c];
                }
                __builtin_nontemporal_store(acc, &Orow[c]);
            }
        }
    }
}

extern "C" void kernel_launch(void* const* d_in, const int* in_sizes, int n_in,
                              void* d_out, int out_size, void* d_ws, size_t ws_size,
                              hipStream_t stream) {
    const float* expert = (const float*)d_in[0];  // [64, 4096]
    const float* gates  = (const float*)d_in[1];  // [16384, 64]
    float* out = (float*)d_out;                   // [16384, 4096]

    dim3 grid(NUM_IMAGES / ROWS_PER_BLOCK);       // 4096 blocks
    dim3 block(256);
    moe_combine_kernel<<<grid, block, 0, stream>>>(expert, gates, out);
}